// Round 2
// baseline (90.556 us; speedup 1.0000x reference)
//
#include <hip/hip_runtime.h>
#include <math.h>

// Quanvolution: x[8192,1,32,32] f32, weights[1,8] f32 -> out[8192,1024] f32
// v3 = v2 with the launch-size fix (in_sizes[0] is an ELEMENT count, not bytes).
// No LDS, no barrier. One block = 4 images, one thread = one 4x4 patch
// (stride 2 over the zero-padded 34x34 grid). Patch pixels come straight from
// global memory as predicated float2 loads (L1/L2 serve the 4x overlap; HBM
// traffic is still one read of x). Trig is computed wave-parallel once per
// block (lanes 0-3: half angles of w0..3, lanes 4-7: full angles of w4..7)
// and broadcast with v_readlane into SGPRs.
//
// Circuit math is bitwise-identical to v1:
//   RY(w[q]) on q=0..3, CNOT ring, second RY layer folded into measurement:
//   <Z_w> = cos(th_w) * Zbar_w - sin(th_w) * Xbar_w, normalized by T = sum st^2.

#define IPB 4  // images per block

__device__ __forceinline__ float rdl(float v, int l) {
    return __int_as_float(__builtin_amdgcn_readlane(__float_as_int(v), l));
}

// RY on qubit with bit-mask M (wire 0 = MSB = mask 8), half-angle cos C / sin S.
#define RY(M, C, S)                                                    \
    {                                                                  \
        _Pragma("unroll") for (int k = 0; k < 16; ++k) {               \
            if ((k & (M)) == 0) {                                      \
                float a0 = st[k], a1 = st[k | (M)];                    \
                st[k]       = (C) * a0 - (S) * a1;                     \
                st[k | (M)] = (S) * a0 + (C) * a1;                     \
            }                                                          \
        }                                                              \
    }

// CNOT(control mask MC, target mask MT): swap st[k] <-> st[k|MT] where control set.
#define CNOT(MC, MT)                                                   \
    {                                                                  \
        _Pragma("unroll") for (int k = 0; k < 16; ++k) {               \
            if ((k & (MC)) != 0 && (k & (MT)) == 0) {                  \
                float t = st[k];                                       \
                st[k] = st[k | (MT)];                                  \
                st[k | (MT)] = t;                                      \
            }                                                          \
        }                                                              \
    }

// Measurement for wire with mask M, full-angle cos CF / sin SF -> OUTV
#define MEAS(M, CF, SF, OUTV)                                          \
    {                                                                  \
        float A = 0.f, X = 0.f;                                        \
        _Pragma("unroll") for (int k = 0; k < 16; ++k) {               \
            if ((k & (M)) == 0) {                                      \
                A += q[k | (M)];                                       \
                X = fmaf(st[k], st[k | (M)], X);                       \
            }                                                          \
        }                                                              \
        float Zb = T - 2.0f * A;                                       \
        OUTV = ((CF) * Zb - (SF) * (2.0f * X)) * inv;                  \
    }

__global__ __launch_bounds__(256) void quanv_kernel(
    const float* __restrict__ x, const float* __restrict__ w,
    float* __restrict__ out)
{
    const int tid  = threadIdx.x;
    const int lane = tid & 63;

    // Wave-parallel trig (8 distinct values, all lanes compute, readlane
    // broadcasts to SGPRs). Same cosf/sinf inputs as v1 -> identical results.
    const float wv  = w[lane & 7];
    const float ang = ((lane & 7) < 4) ? wv * 0.5f : wv;
    const float cv = cosf(ang);
    const float sv = sinf(ang);
    const float c0 = rdl(cv, 0), c1 = rdl(cv, 1), c2 = rdl(cv, 2), c3 = rdl(cv, 3);
    const float s0 = rdl(sv, 0), s1 = rdl(sv, 1), s2 = rdl(sv, 2), s3 = rdl(sv, 3);
    const float cf0 = rdl(cv, 4), cf1 = rdl(cv, 5), cf2 = rdl(cv, 6), cf3 = rdl(cv, 7);
    const float sf0 = rdl(sv, 4), sf1 = rdl(sv, 5), sf2 = rdl(sv, 6), sf3 = rdl(sv, 7);

    // This thread's patch position (py,px in 16x16 grid of stride-2 patches).
    const int py = tid >> 4, px = tid & 15;
    const int r0 = py << 1, cc0 = px << 1;
    const bool cfull = (px < 15);   // px==15 -> cols 32,33 are zero pad
    const int rlim = 32 - r0;       // dr < rlim -> row in bounds (py==15: dr 2,3 pad)

    for (int i = 0; i < IPB; ++i) {
        const size_t b = (size_t)blockIdx.x * IPB + i;
        const float* __restrict__ pp = x + b * 1024 + r0 * 32 + cc0;

        // Gather 4x4 patch (row-major -> state index k = dr*4+dc), zero-padded.
        float st[16];
#pragma unroll
        for (int dr = 0; dr < 4; ++dr) {
            float2 u0 = make_float2(0.f, 0.f);
            float2 u1 = make_float2(0.f, 0.f);
            if (dr < rlim) {
                u0 = *(const float2*)(pp + dr * 32);
                if (cfull) u1 = *(const float2*)(pp + dr * 32 + 2);
            }
            st[dr * 4 + 0] = u0.x;
            st[dr * 4 + 1] = u0.y;
            st[dr * 4 + 2] = u1.x;
            st[dr * 4 + 3] = u1.y;
        }

        // Layer 1: RY on qubits 0..3 (masks 8,4,2,1).
        RY(8, c0, s0)
        RY(4, c1, s1)
        RY(2, c2, s2)
        RY(1, c3, s3)

        // CNOT ring: (0,1),(1,2),(2,3),(3,0).
        CNOT(8, 4)
        CNOT(4, 2)
        CNOT(2, 1)
        CNOT(1, 8)

        // Probabilities and norm (orthogonal circuit => T == ||v||^2 up to rounding).
        float q[16];
#pragma unroll
        for (int k = 0; k < 16; ++k) q[k] = st[k] * st[k];
        float T = ((q[0] + q[1]) + (q[2] + q[3])) + ((q[4] + q[5]) + (q[6] + q[7])) +
                  (((q[8] + q[9]) + (q[10] + q[11])) + ((q[12] + q[13]) + (q[14] + q[15])));
        float inv = 1.0f / T;

        float e0, e1, e2, e3;
        MEAS(8, cf0, sf0, e0)
        MEAS(4, cf1, sf1, e1)
        MEAS(2, cf2, sf2, e2)
        MEAS(1, cf3, sf3, e3)

        // out[b, tid*4 + w] -- coalesced float4 store.
        *(float4*)(out + b * 1024 + (tid << 2)) = make_float4(e0, e1, e2, e3);
    }
}

extern "C" void kernel_launch(void* const* d_in, const int* in_sizes, int n_in,
                              void* d_out, int out_size, void* d_ws, size_t ws_size,
                              hipStream_t stream) {
    const float* x = (const float*)d_in[0];
    const float* w = (const float*)d_in[1];
    float* out = (float*)d_out;
    const int B = in_sizes[0] >> 10;  // in_sizes[0] = element count; 1024 f32 per image
    quanv_kernel<<<B / IPB, 256, 0, stream>>>(x, w, out);
}